// Round 1
// 857.421 us; speedup vs baseline: 1.1734x; 1.1734x over previous
//
#include <hip/hip_runtime.h>

// BilinearAttention B=8, N=2048, H=1024 — MFMA f16-split pipeline, v2:
// global_load_lds staging with XOR-swizzled source/read (no reg-staging, no unpack).
//
// Global plane-grouped format for all GEMM operands: rows of 128-byte groups,
// group g covers k=[g*32,g*32+32) as [32 hi f16 | 32 lo f16]  (split operands)
// or k=[g*64,g*64+64) as [64 f16]                             (plain f16 operands).
// Every matrix here has a 4096-byte row stride and 32 k-groups.
//
//   prep_v : value fp32 -> Vp planes [b][n][g][hi|lo]  +  Vt f16 [b][h][n]
//   prep_w : W fp32 [k][n] -> Wtp planes [n][g][hi|lo]
//   prep_q : query fp32 -> Qp planes [b*m][g][hi|lo]   (parked in attn region)
//   gemm<1>: interP = split(Qp) @ Wtp   (3-MFMA split) -> planes in out region
//   gemm<2>: logits = relu(interP @ Vp^T) masked -> attn fp32
//   softmax: rowwise in place + f16 copy attnH (parked in dead Vp region)
//   gemm<3>: out = attnH @ Vt  (plain f16 MFMA)

typedef _Float16 half8 __attribute__((ext_vector_type(8)));
typedef float f32x4 __attribute__((ext_vector_type(4)));
typedef unsigned short u16;
typedef unsigned int u32;

#define BATCH 8
#define SEQ   2048
#define HID   1024
#define MINV  (-1e9f)

#define AS1 __attribute__((address_space(1)))
#define AS3 __attribute__((address_space(3)))

__device__ __forceinline__ u16 h2u(_Float16 h) { return __builtin_bit_cast(u16, h); }

// split fp32 -> (hi,lo) f16 packed into one u32 (hi in low half)
__device__ __forceinline__ u32 packhl(float x) {
    _Float16 h = (_Float16)x;
    _Float16 l = (_Float16)(x - (float)h);
    return (u32)h2u(h) | ((u32)h2u(l) << 16);
}

__device__ __forceinline__ void gload16(const char* g, AS3 char* l) {
    __builtin_amdgcn_global_load_lds((const AS1 void*)g, (AS3 void*)l, 16, 0, 0);
}

// ---------------------------------------------------------------------------
// prep_v: 64x64 tiles. Writes Vp (plane-grouped) coalesced and Vt (f16,
// transposed to [b][h][n]) via LDS transpose.
// ---------------------------------------------------------------------------
__global__ __launch_bounds__(256) void prep_v(const float* __restrict__ V,
                                              u16* __restrict__ Vp,
                                              u16* __restrict__ Vt)
{
    __shared__ __align__(16) u16 lt[64 * 72];
    const int b = blockIdx.z, n0 = blockIdx.y * 64, h0 = blockIdx.x * 64;
    const int t = threadIdx.x;
    const int r = t >> 4, c4 = (t & 15) * 4;
#pragma unroll
    for (int it = 0; it < 4; ++it) {
        const int rr = r + it * 16;
        const float4 x = *(const float4*)(V + ((size_t)b * SEQ + n0 + rr) * HID + h0 + c4);
        const float xs[4] = {x.x, x.y, x.z, x.w};
        u32 p[4];
#pragma unroll
        for (int e = 0; e < 4; ++e) {
            p[e] = packhl(xs[e]);
            lt[(c4 + e) * 72 + rr] = (u16)p[e];
        }
        const int g = (h0 + c4) >> 5, j = c4 & 31;
        u16* base = Vp + (((size_t)b * SEQ + n0 + rr) * 32 + g) * 64;
        *(uint2*)(base + j) = make_uint2((p[0] & 0xffffu) | (p[1] << 16),
                                         (p[2] & 0xffffu) | (p[3] << 16));
        *(uint2*)(base + 32 + j) = make_uint2((p[0] >> 16) | (p[1] & 0xffff0000u),
                                              (p[2] >> 16) | (p[3] & 0xffff0000u));
    }
    __syncthreads();
    const int hr = t >> 2, cc = (t & 3) * 2;
    uint4 v0 = *(const uint4*)&lt[hr * 72 + cc * 8];
    uint4 v1 = *(const uint4*)&lt[hr * 72 + cc * 8 + 8];
    u16* dst = Vt + ((size_t)b * HID + h0 + hr) * SEQ + n0 + cc * 8;
    *(uint4*)dst = v0;
    *(uint4*)(dst + 8) = v1;
}

// ---------------------------------------------------------------------------
// prep_w: W [k][n] fp32 -> Wtp planes [n][g][hi|lo], 64x64 LDS transpose.
// ---------------------------------------------------------------------------
__global__ __launch_bounds__(256) void prep_w(const float* __restrict__ W,
                                              u16* __restrict__ Wtp)
{
    __shared__ __align__(16) u32 lt[64 * 68];
    const int n0 = blockIdx.x * 64, k0 = blockIdx.y * 64;
    const int t = threadIdx.x;
    const int r = t >> 4, c4 = (t & 15) * 4;
#pragma unroll
    for (int it = 0; it < 4; ++it) {
        const int rr = r + it * 16;
        const float4 x = *(const float4*)(W + (size_t)(k0 + rr) * HID + n0 + c4);
        const float xs[4] = {x.x, x.y, x.z, x.w};
#pragma unroll
        for (int e = 0; e < 4; ++e) lt[(c4 + e) * 68 + rr] = packhl(xs[e]);
    }
    __syncthreads();
    const int n = t >> 2;
#pragma unroll
    for (int s = 0; s < 4; ++s) {
        const int ci = (t & 3) + s * 4;
        uint4 v = *(const uint4*)&lt[n * 68 + ci * 4];
        const int k = k0 + ci * 4;
        u16* base = Wtp + (((size_t)n0 + n) * 32 + (k >> 5)) * 64;
        const int j = k & 31;
        *(uint2*)(base + j) = make_uint2((v.x & 0xffffu) | (v.y << 16),
                                         (v.z & 0xffffu) | (v.w << 16));
        *(uint2*)(base + 32 + j) = make_uint2((v.x >> 16) | (v.y & 0xffff0000u),
                                              (v.z >> 16) | (v.w & 0xffff0000u));
    }
}

// ---------------------------------------------------------------------------
// prep_q: query fp32 [row][1024] -> Qp planes [row][g][hi|lo]. One block/row.
// ---------------------------------------------------------------------------
__global__ __launch_bounds__(256) void prep_q(const float* __restrict__ Q,
                                              u16* __restrict__ Qp)
{
    const size_t row = blockIdx.x;
    const int t = threadIdx.x;
    const float4 x = ((const float4*)(Q + row * HID))[t];
    const u32 p0 = packhl(x.x), p1 = packhl(x.y), p2 = packhl(x.z), p3 = packhl(x.w);
    const int k = t * 4;
    u16* base = Qp + (row * 32 + (k >> 5)) * 64;
    const int j = k & 31;
    *(uint2*)(base + j) = make_uint2((p0 & 0xffffu) | (p1 << 16),
                                     (p2 & 0xffffu) | (p3 << 16));
    *(uint2*)(base + 32 + j) = make_uint2((p0 >> 16) | (p1 & 0xffff0000u),
                                          (p2 >> 16) | (p3 & 0xffff0000u));
}

// ---------------------------------------------------------------------------
// MFMA GEMM, 128x128 block tile, 4 waves (each 64x64 = 4x4 MFMA tiles).
// A/B staged via global_load_lds (16B/lane, linear LDS dest). LDS rows are
// 128 B; the within-row offset is XOR-swizzled by (row&7)<<4 on BOTH the
// per-lane global source and the ds_read address (involution -> consistent;
// gives 2-way-max bank aliasing on the b128 fragment reads, which is free).
// MODE 1: A,B split planes, C plane-grouped out        [gemm1]
// MODE 2: A,B split planes, relu+mask epilogue, C fp32 [gemm2]
// MODE 3: A,B plain f16 (BK=64), C fp32                [gemm3]
// All operands here: row stride 4096 B, 32 k-steps.
// ---------------------------------------------------------------------------
template <int MODE>
__global__ __launch_bounds__(256) void gemm_mfma(
    const char* __restrict__ Abase, const char* __restrict__ Bbase,
    void* __restrict__ Cbase, const int* __restrict__ Mbase,
    int ldc, long sAb, long sBb, long sC, long sM)
{
    constexpr bool SPLIT = (MODE != 3);
    const int b = blockIdx.z;
    const int tid = threadIdx.x;
    const int m0 = blockIdx.y * 128, n0 = blockIdx.x * 128;

    __shared__ __align__(16) char smem[32768];   // A tile 16KB | B tile 16KB

    const int w = tid >> 6, l = tid & 63;
    const int wr = (w >> 1) * 64, wc = (w & 1) * 64;
    const int lm = l & 15, q = l >> 4;

    const char* Ab = Abase + (long)b * sAb;
    const char* Bb = Bbase + (long)b * sBb;

    // staging source offsets (k-invariant): LDS pos -> inverse-swizzled global
    size_t aoff[4], boff[4];
    int dsto[4];
#pragma unroll
    for (int it = 0; it < 4; ++it) {
        dsto[it] = it * 4096 + w * 1024;              // wave-uniform LDS base
        const int off = dsto[it] + l * 16;            // this lane's LDS slot
        const int row = off >> 7;
        const int swi = (off & 127) ^ ((row & 7) << 4);
        aoff[it] = (size_t)(m0 + row) * 4096 + swi;
        boff[it] = (size_t)(n0 + row) * 4096 + swi;
    }

    // fragment-read swizzled within-row offset (row&7 == lm&7 for all frags)
    const int wofs = (q * 16) ^ ((lm & 7) << 4);

    f32x4 acc[4][4];
#pragma unroll
    for (int i = 0; i < 4; ++i)
#pragma unroll
        for (int j = 0; j < 4; ++j) acc[i][j] = (f32x4){0.f, 0.f, 0.f, 0.f};

    AS3 char* ldsA = (AS3 char*)smem;
    AS3 char* ldsB = ldsA + 16384;
    const char* At = smem;
    const char* Bt = smem + 16384;

    for (int ks = 0; ks < 32; ++ks) {
        __syncthreads();                      // prior reads done before overwrite
#pragma unroll
        for (int it = 0; it < 4; ++it) {
            gload16(Ab + aoff[it] + (size_t)ks * 128, ldsA + dsto[it]);
            gload16(Bb + boff[it] + (size_t)ks * 128, ldsB + dsto[it]);
        }
        __syncthreads();                      // vmcnt(0) drain: tiles resident

        if constexpr (SPLIT) {
            half8 af[4], alf[4];
#pragma unroll
            for (int i = 0; i < 4; ++i) {
                const char* rp = At + (wr + i * 16 + lm) * 128;
                af[i]  = *(const half8*)(rp + wofs);
                alf[i] = *(const half8*)(rp + (wofs ^ 64));
            }
#pragma unroll
            for (int j = 0; j < 4; ++j) {
                const char* cp = Bt + (wc + j * 16 + lm) * 128;
                half8 bf  = *(const half8*)(cp + wofs);
                half8 blf = *(const half8*)(cp + (wofs ^ 64));
#pragma unroll
                for (int i = 0; i < 4; ++i) {
                    acc[i][j] = __builtin_amdgcn_mfma_f32_16x16x32_f16(alf[i], bf, acc[i][j], 0, 0, 0);
                    acc[i][j] = __builtin_amdgcn_mfma_f32_16x16x32_f16(af[i], blf, acc[i][j], 0, 0, 0);
                    acc[i][j] = __builtin_amdgcn_mfma_f32_16x16x32_f16(af[i], bf, acc[i][j], 0, 0, 0);
                }
            }
        } else {
            half8 af[2][4];
#pragma unroll
            for (int i = 0; i < 4; ++i) {
                const char* rp = At + (wr + i * 16 + lm) * 128;
                af[0][i] = *(const half8*)(rp + wofs);
                af[1][i] = *(const half8*)(rp + (wofs ^ 64));
            }
#pragma unroll
            for (int kk = 0; kk < 2; ++kk) {
#pragma unroll
                for (int j = 0; j < 4; ++j) {
                    const char* cp = Bt + (wc + j * 16 + lm) * 128;
                    half8 bf = *(const half8*)(cp + (wofs ^ (kk * 64)));
#pragma unroll
                    for (int i = 0; i < 4; ++i)
                        acc[i][j] = __builtin_amdgcn_mfma_f32_16x16x32_f16(af[kk][i], bf, acc[i][j], 0, 0, 0);
                }
            }
        }
    }

    // ---- epilogue ----  C/D map: col = lane&15, row = (lane>>4)*4 + reg
#pragma unroll
    for (int i = 0; i < 4; ++i) {
#pragma unroll
        for (int r = 0; r < 4; ++r) {
            const int grow = m0 + wr + i * 16 + q * 4 + r;
#pragma unroll
            for (int j = 0; j < 4; ++j) {
                const int gcol = n0 + wc + j * 16 + lm;
                const float v = acc[i][j][r];
                if constexpr (MODE == 1) {
                    const u32 p = packhl(v);
                    u16* base = (u16*)Cbase + ((size_t)grow * (ldc >> 5) + (gcol >> 5)) * 64;
                    base[gcol & 31] = (u16)p;
                    base[32 + (gcol & 31)] = (u16)(p >> 16);
                } else if constexpr (MODE == 2) {
                    const int mv = Mbase[(long)b * sM + (long)grow * ldc + gcol];
                    ((float*)Cbase)[(long)b * sC + (long)grow * ldc + gcol] =
                        (mv > 0) ? fmaxf(v, 0.f) : MINV;
                } else {
                    ((float*)Cbase)[(long)b * sC + (long)grow * ldc + gcol] = v;
                }
            }
        }
    }
}

// ---------------------------------------------------------------------------
// Row softmax over 2048 elements, in place + f16 copy for gemm3.
// ---------------------------------------------------------------------------
__global__ __launch_bounds__(256) void softmax2048(float* __restrict__ attn,
                                                   u16* __restrict__ attnH)
{
    const long row = blockIdx.x;
    float* p = attn + row * 2048;
    const int tid = threadIdx.x;

    float4 v0 = ((const float4*)p)[tid];
    float4 v1 = ((const float4*)p)[tid + 256];

    float mx = fmaxf(fmaxf(fmaxf(v0.x, v0.y), fmaxf(v0.z, v0.w)),
                     fmaxf(fmaxf(v1.x, v1.y), fmaxf(v1.z, v1.w)));
#pragma unroll
    for (int o = 32; o >= 1; o >>= 1)
        mx = fmaxf(mx, __shfl_xor(mx, o, 64));

    __shared__ float redm[4];
    __shared__ float reds[4];
    const int wid = tid >> 6, lane = tid & 63;
    if (lane == 0) redm[wid] = mx;
    __syncthreads();
    mx = fmaxf(fmaxf(redm[0], redm[1]), fmaxf(redm[2], redm[3]));

    float e[8];
    e[0] = __expf(v0.x - mx); e[1] = __expf(v0.y - mx);
    e[2] = __expf(v0.z - mx); e[3] = __expf(v0.w - mx);
    e[4] = __expf(v1.x - mx); e[5] = __expf(v1.y - mx);
    e[6] = __expf(v1.z - mx); e[7] = __expf(v1.w - mx);

    float s = ((e[0] + e[1]) + (e[2] + e[3])) + ((e[4] + e[5]) + (e[6] + e[7]));
#pragma unroll
    for (int o = 32; o >= 1; o >>= 1)
        s += __shfl_xor(s, o, 64);
    if (lane == 0) reds[wid] = s;
    __syncthreads();
    s = (reds[0] + reds[1]) + (reds[2] + reds[3]);

    const float inv = 1.0f / s;
    float o0 = e[0] * inv, o1 = e[1] * inv, o2 = e[2] * inv, o3 = e[3] * inv;
    float o4 = e[4] * inv, o5 = e[5] * inv, o6 = e[6] * inv, o7 = e[7] * inv;
    ((float4*)p)[tid]       = make_float4(o0, o1, o2, o3);
    ((float4*)p)[tid + 256] = make_float4(o4, o5, o6, o7);

    u16* ph = attnH + row * 2048;
    ((uint2*)ph)[tid] =
        make_uint2((u32)h2u((_Float16)o0) | ((u32)h2u((_Float16)o1) << 16),
                   (u32)h2u((_Float16)o2) | ((u32)h2u((_Float16)o3) << 16));
    ((uint2*)ph)[tid + 256] =
        make_uint2((u32)h2u((_Float16)o4) | ((u32)h2u((_Float16)o5) << 16),
                   (u32)h2u((_Float16)o6) | ((u32)h2u((_Float16)o7) << 16));
}

extern "C" void kernel_launch(void* const* d_in, const int* in_sizes, int n_in,
                              void* d_out, int out_size, void* d_ws, size_t ws_size,
                              hipStream_t stream)
{
    (void)in_sizes; (void)n_in; (void)out_size; (void)ws_size;

    const float* query = (const float*)d_in[0];  // B,N,H
    const float* value = (const float*)d_in[1];  // B,N,H
    const int*   mask  = (const int*)d_in[2];    // B,N,N
    const float* W     = (const float*)d_in[3];  // H,H

    float* out  = (float*)d_out;                           // B*N*H
    float* attn = out + (size_t)BATCH * SEQ * HID;         // B*N*N

    // workspace: Vp 64MB | Vt 32MB | Wtp 4MB   (100MB total, same as before)
    u16* Vp  = (u16*)d_ws;
    u16* Vt  = (u16*)((char*)d_ws + ((size_t)64 << 20));
    u16* Wtp = (u16*)((char*)d_ws + ((size_t)96 << 20));

    // region reuse (stream-ordered, no overlap in time):
    u16* interP = (u16*)d_out;   // out region; dead once gemm3 writes out
    u16* Qp     = (u16*)attn;    // attn region; dead once gemm2 writes attn
    u16* attnH  = Vp;            // Vp region;  dead once gemm2 completes

    prep_v<<<dim3(HID / 64, SEQ / 64, BATCH), 256, 0, stream>>>(value, Vp, Vt);
    prep_w<<<dim3(HID / 64, HID / 64, 1), 256, 0, stream>>>(W, Wtp);
    prep_q<<<dim3(BATCH * SEQ), 256, 0, stream>>>(query, Qp);

    // gemm1: interP = split(Qp) @ Wtp^T   M=16384 N=1024 K=1024
    gemm_mfma<1><<<dim3(HID / 128, (BATCH * SEQ) / 128, 1), 256, 0, stream>>>(
        (const char*)Qp, (const char*)Wtp, interP, nullptr,
        HID, 0, 0, 0, 0);

    // gemm2: logits = relu(interP @ Vp^T) masked -> attn (fp32)
    gemm_mfma<2><<<dim3(SEQ / 128, SEQ / 128, BATCH), 256, 0, stream>>>(
        (const char*)interP, (const char*)Vp, attn, mask,
        SEQ, (long)SEQ * 4096, (long)SEQ * 4096, (long)SEQ * SEQ, (long)SEQ * SEQ);

    softmax2048<<<dim3(BATCH * SEQ), 256, 0, stream>>>(attn, attnH);

    // gemm3: out = attnH @ Vt   M=2048 N=1024 K=2048 (plain f16, BK=64)
    gemm_mfma<3><<<dim3(HID / 128, SEQ / 128, BATCH), 256, 0, stream>>>(
        (const char*)attnH, (const char*)Vt, out, nullptr,
        HID, (long)SEQ * 4096, (long)HID * 4096, (long)SEQ * HID, 0);
}

// Round 2
// 738.283 us; speedup vs baseline: 1.3627x; 1.1614x over previous
//
#include <hip/hip_runtime.h>

// BilinearAttention B=8, N=2048, H=1024 — MFMA f16-split pipeline, v3:
// 256x256 8-wave double-buffered phase schedule (T3+T4+T5) on top of the
// v2 global_load_lds + XOR-swizzle staging.
//
// Global plane-grouped format for all GEMM operands: rows of 128-byte groups,
// group g covers k=[g*32,g*32+32) as [32 hi f16 | 32 lo f16]  (split operands)
// or k=[g*64,g*64+64) as [64 f16]                             (plain f16 operands).
// Every matrix here has a 4096-byte row stride and 32 k-groups.
//
//   prep_v : value fp32 -> Vp planes [b][n][g][hi|lo]  +  Vt f16 [b][h][n]
//   prep_w : W fp32 [k][n] -> Wtp planes [n][g][hi|lo]
//   prep_q : query fp32 -> Qp planes [b*m][g][hi|lo]   (parked in attn region)
//   gemm<1>: interP = split(Qp) @ Wtp   (3-MFMA split) -> planes in out region
//   gemm<2>: logits = relu(interP @ Vp^T) masked -> attn fp32
//   softmax: rowwise in place + f16 copy attnH (parked in dead Vp region)
//   gemm<3>: out = attnH @ Vt  (plain f16 MFMA)

typedef _Float16 half8 __attribute__((ext_vector_type(8)));
typedef float f32x4 __attribute__((ext_vector_type(4)));
typedef unsigned short u16;
typedef unsigned int u32;

#define BATCH 8
#define SEQ   2048
#define HID   1024
#define MINV  (-1e9f)

#define AS1 __attribute__((address_space(1)))
#define AS3 __attribute__((address_space(3)))

__device__ __forceinline__ u16 h2u(_Float16 h) { return __builtin_bit_cast(u16, h); }

// split fp32 -> (hi,lo) f16 packed into one u32 (hi in low half)
__device__ __forceinline__ u32 packhl(float x) {
    _Float16 h = (_Float16)x;
    _Float16 l = (_Float16)(x - (float)h);
    return (u32)h2u(h) | ((u32)h2u(l) << 16);
}

__device__ __forceinline__ void gload16(const char* g, AS3 char* l) {
    __builtin_amdgcn_global_load_lds((const AS1 void*)g, (AS3 void*)l, 16, 0, 0);
}

// ---------------------------------------------------------------------------
// prep_v: 64x64 tiles. Writes Vp (plane-grouped) coalesced and Vt (f16,
// transposed to [b][h][n]) via LDS transpose.
// ---------------------------------------------------------------------------
__global__ __launch_bounds__(256) void prep_v(const float* __restrict__ V,
                                              u16* __restrict__ Vp,
                                              u16* __restrict__ Vt)
{
    __shared__ __align__(16) u16 lt[64 * 72];
    const int b = blockIdx.z, n0 = blockIdx.y * 64, h0 = blockIdx.x * 64;
    const int t = threadIdx.x;
    const int r = t >> 4, c4 = (t & 15) * 4;
#pragma unroll
    for (int it = 0; it < 4; ++it) {
        const int rr = r + it * 16;
        const float4 x = *(const float4*)(V + ((size_t)b * SEQ + n0 + rr) * HID + h0 + c4);
        const float xs[4] = {x.x, x.y, x.z, x.w};
        u32 p[4];
#pragma unroll
        for (int e = 0; e < 4; ++e) {
            p[e] = packhl(xs[e]);
            lt[(c4 + e) * 72 + rr] = (u16)p[e];
        }
        const int g = (h0 + c4) >> 5, j = c4 & 31;
        u16* base = Vp + (((size_t)b * SEQ + n0 + rr) * 32 + g) * 64;
        *(uint2*)(base + j) = make_uint2((p[0] & 0xffffu) | (p[1] << 16),
                                         (p[2] & 0xffffu) | (p[3] << 16));
        *(uint2*)(base + 32 + j) = make_uint2((p[0] >> 16) | (p[1] & 0xffff0000u),
                                              (p[2] >> 16) | (p[3] & 0xffff0000u));
    }
    __syncthreads();
    const int hr = t >> 2, cc = (t & 3) * 2;
    uint4 v0 = *(const uint4*)&lt[hr * 72 + cc * 8];
    uint4 v1 = *(const uint4*)&lt[hr * 72 + cc * 8 + 8];
    u16* dst = Vt + ((size_t)b * HID + h0 + hr) * SEQ + n0 + cc * 8;
    *(uint4*)dst = v0;
    *(uint4*)(dst + 8) = v1;
}

// ---------------------------------------------------------------------------
// prep_w: W [k][n] fp32 -> Wtp planes [n][g][hi|lo], 64x64 LDS transpose.
// ---------------------------------------------------------------------------
__global__ __launch_bounds__(256) void prep_w(const float* __restrict__ W,
                                              u16* __restrict__ Wtp)
{
    __shared__ __align__(16) u32 lt[64 * 68];
    const int n0 = blockIdx.x * 64, k0 = blockIdx.y * 64;
    const int t = threadIdx.x;
    const int r = t >> 4, c4 = (t & 15) * 4;
#pragma unroll
    for (int it = 0; it < 4; ++it) {
        const int rr = r + it * 16;
        const float4 x = *(const float4*)(W + (size_t)(k0 + rr) * HID + n0 + c4);
        const float xs[4] = {x.x, x.y, x.z, x.w};
#pragma unroll
        for (int e = 0; e < 4; ++e) lt[(c4 + e) * 68 + rr] = packhl(xs[e]);
    }
    __syncthreads();
    const int n = t >> 2;
#pragma unroll
    for (int s = 0; s < 4; ++s) {
        const int ci = (t & 3) + s * 4;
        uint4 v = *(const uint4*)&lt[n * 68 + ci * 4];
        const int k = k0 + ci * 4;
        u16* base = Wtp + (((size_t)n0 + n) * 32 + (k >> 5)) * 64;
        const int j = k & 31;
        *(uint2*)(base + j) = make_uint2((v.x & 0xffffu) | (v.y << 16),
                                         (v.z & 0xffffu) | (v.w << 16));
        *(uint2*)(base + 32 + j) = make_uint2((v.x >> 16) | (v.y & 0xffff0000u),
                                              (v.z >> 16) | (v.w & 0xffff0000u));
    }
}

// ---------------------------------------------------------------------------
// prep_q: query fp32 [row][1024] -> Qp planes [row][g][hi|lo]. One block/row.
// ---------------------------------------------------------------------------
__global__ __launch_bounds__(256) void prep_q(const float* __restrict__ Q,
                                              u16* __restrict__ Qp)
{
    const size_t row = blockIdx.x;
    const int t = threadIdx.x;
    const float4 x = ((const float4*)(Q + row * HID))[t];
    const u32 p0 = packhl(x.x), p1 = packhl(x.y), p2 = packhl(x.z), p3 = packhl(x.w);
    const int k = t * 4;
    u16* base = Qp + (row * 32 + (k >> 5)) * 64;
    const int j = k & 31;
    *(uint2*)(base + j) = make_uint2((p0 & 0xffffu) | (p1 << 16),
                                     (p2 & 0xffffu) | (p3 << 16));
    *(uint2*)(base + 32 + j) = make_uint2((p0 >> 16) | (p1 & 0xffff0000u),
                                          (p2 >> 16) | (p3 & 0xffff0000u));
}

// ---------------------------------------------------------------------------
// one 2xM x 4xN MFMA cluster for m-pair p (split: 3 MFMAs/frag; plain: 2)
// ---------------------------------------------------------------------------
template <bool SPLIT>
__device__ __forceinline__ void mfma_block(f32x4 (&acc)[8][4], int p,
                                           const half8 (&ah)[2], const half8 (&al)[2],
                                           const half8 (&bh)[4], const half8 (&bl)[4])
{
#pragma unroll
    for (int j = 0; j < 4; ++j)
#pragma unroll
        for (int e = 0; e < 2; ++e) {
            f32x4 c = acc[p * 2 + e][j];
            if constexpr (SPLIT) {
                c = __builtin_amdgcn_mfma_f32_16x16x32_f16(al[e], bh[j], c, 0, 0, 0);
                c = __builtin_amdgcn_mfma_f32_16x16x32_f16(ah[e], bl[j], c, 0, 0, 0);
                c = __builtin_amdgcn_mfma_f32_16x16x32_f16(ah[e], bh[j], c, 0, 0, 0);
            } else {
                c = __builtin_amdgcn_mfma_f32_16x16x32_f16(ah[e], bh[j], c, 0, 0, 0);
                c = __builtin_amdgcn_mfma_f32_16x16x32_f16(al[e], bl[j], c, 0, 0, 0);
            }
            acc[p * 2 + e][j] = c;
        }
}

// ---------------------------------------------------------------------------
// MFMA GEMM, 256x256 block tile, 8 waves (2x4), double-buffered LDS (128KB),
// 4-phase-per-K-step schedule with raw barriers + counted waits + setprio.
// A/B staged via global_load_lds (16B/lane, linear LDS dest). LDS rows are
// 128 B; within-row offset XOR-swizzled by (row&7)<<4 on BOTH the per-lane
// global source and the ds_read address (involution -> consistent).
// Per K-step (one 128B group): phase 1 reads B frags + A pair 0 and issues
// the ENTIRE next K-step's 8 global_load_lds into the other buffer; phases
// 2-4 read A pairs 1-3. vmcnt(0) only at the K-step boundary (~96 MFMAs of
// cover after issue) — loads stay in flight across 6 barriers.
// MODE 1: A,B split planes, C plane-grouped out        [gemm1]
// MODE 2: A,B split planes, relu+mask epilogue, C fp32 [gemm2]
// MODE 3: A,B plain f16 (64 k/group), C fp32           [gemm3]
// All operands: row stride 4096 B, 32 k-groups.
// ---------------------------------------------------------------------------
template <int MODE>
__global__ __launch_bounds__(512, 2) void gemm_mfma(
    const char* __restrict__ Abase, const char* __restrict__ Bbase,
    void* __restrict__ Cbase, const int* __restrict__ Mbase,
    int ldc, long sAb, long sBb, long sC, long sM)
{
    constexpr bool SPLIT = (MODE != 3);
    extern __shared__ __align__(16) char smem[];   // 2 x (A 32KB | B 32KB)

    // bijective XCD-aware block swizzle (all grids have nwg % 8 == 0)
    const int nx = gridDim.x, ny = gridDim.y;
    const int nxy = nx * ny;
    int wg = blockIdx.x + nx * (blockIdx.y + ny * blockIdx.z);
    const int cpx = (nxy * gridDim.z) >> 3;
    wg = (wg & 7) * cpx + (wg >> 3);
    const int bz = wg / nxy;
    const int rem = wg - bz * nxy;
    const int m0 = (rem / nx) * 256, n0 = (rem % nx) * 256;

    const int tid = threadIdx.x;
    const int w = tid >> 6, l = tid & 63;
    const int wm = w >> 2, wn = w & 3;            // 2 x 4 wave grid -> 128x64/wave
    const int lm = l & 15, q = l >> 4;

    const char* Ab = Abase + (long)bz * sAb;
    const char* Bb = Bbase + (long)bz * sBb;

    // staging offsets (k-invariant): LDS slot -> inverse-swizzled global
    size_t aoffs[4], boffs[4];
    int dsto[4];
#pragma unroll
    for (int it = 0; it < 4; ++it) {
        const int off = it * 8192 + tid * 16;     // 512 thr x 16B x 4 = 32KB tile
        dsto[it] = off;
        const int row = off >> 7;
        const int swi = (off & 127) ^ ((row & 7) << 4);
        aoffs[it] = (size_t)(m0 + row) * 4096 + swi;
        boffs[it] = (size_t)(n0 + row) * 4096 + swi;
    }
    // fragment-read swizzled within-row offset (row&7 == lm&7 for all frags)
    const int wofs = (q * 16) ^ ((lm & 7) << 4);

    f32x4 acc[8][4];
#pragma unroll
    for (int i = 0; i < 8; ++i)
#pragma unroll
        for (int j = 0; j < 4; ++j) acc[i][j] = (f32x4){0.f, 0.f, 0.f, 0.f};

    AS3 char* lds = (AS3 char*)smem;

    // prologue: stage K-step 0 into buf 0
#pragma unroll
    for (int it = 0; it < 4; ++it) gload16(Ab + aoffs[it], lds + dsto[it]);
#pragma unroll
    for (int it = 0; it < 4; ++it) gload16(Bb + boffs[it], lds + 32768 + dsto[it]);
    asm volatile("s_waitcnt vmcnt(0)" ::: "memory");
    __builtin_amdgcn_s_barrier();

    half8 bh[4], bl[4], ah[2], al[2];

    for (int ks = 0; ks < 32; ++ks) {
        const int cur = ks & 1;
        const char* At = smem + cur * 65536;
        const char* Bt = At + 32768;

        // ---- phase 1: B frags + A pair 0; issue next K-step's loads ----
#pragma unroll
        for (int j = 0; j < 4; ++j) {
            const char* cp = Bt + (wn * 64 + j * 16 + lm) * 128;
            bh[j] = *(const half8*)(cp + wofs);
            bl[j] = *(const half8*)(cp + (wofs ^ 64));
        }
#pragma unroll
        for (int e = 0; e < 2; ++e) {
            const char* rp = At + (wm * 128 + e * 16 + lm) * 128;
            ah[e] = *(const half8*)(rp + wofs);
            al[e] = *(const half8*)(rp + (wofs ^ 64));
        }
        if (ks + 1 < 32) {
            AS3 char* ldsn = lds + (cur ^ 1) * 65536;
            const size_t kb = (size_t)(ks + 1) * 128;
#pragma unroll
            for (int it = 0; it < 4; ++it) gload16(Ab + aoffs[it] + kb, ldsn + dsto[it]);
#pragma unroll
            for (int it = 0; it < 4; ++it) gload16(Bb + boffs[it] + kb, ldsn + 32768 + dsto[it]);
        }
        __builtin_amdgcn_s_barrier();
        asm volatile("s_waitcnt lgkmcnt(0)" ::: "memory");
        __builtin_amdgcn_s_setprio(1);
        mfma_block<SPLIT>(acc, 0, ah, al, bh, bl);
        __builtin_amdgcn_s_setprio(0);
        __builtin_amdgcn_s_barrier();

        // ---- phases 2-4: A pairs 1-3 ----
#pragma unroll
        for (int p = 1; p < 4; ++p) {
#pragma unroll
            for (int e = 0; e < 2; ++e) {
                const char* rp = At + (wm * 128 + (p * 2 + e) * 16 + lm) * 128;
                ah[e] = *(const half8*)(rp + wofs);
                al[e] = *(const half8*)(rp + (wofs ^ 64));
            }
            __builtin_amdgcn_s_barrier();
            asm volatile("s_waitcnt lgkmcnt(0)" ::: "memory");
            __builtin_amdgcn_s_setprio(1);
            mfma_block<SPLIT>(acc, p, ah, al, bh, bl);
            __builtin_amdgcn_s_setprio(0);
            if (p < 3) __builtin_amdgcn_s_barrier();
        }
        // K-step boundary: next buffer's loads (issued in phase 1) must land.
        asm volatile("s_waitcnt vmcnt(0)" ::: "memory");
        __builtin_amdgcn_s_barrier();
    }

    // ---- epilogue ----  C/D map: col = lane&15, row = (lane>>4)*4 + reg
#pragma unroll
    for (int i = 0; i < 8; ++i) {
#pragma unroll
        for (int r = 0; r < 4; ++r) {
            const int grow = m0 + wm * 128 + i * 16 + q * 4 + r;
#pragma unroll
            for (int j = 0; j < 4; ++j) {
                const int gcol = n0 + wn * 64 + j * 16 + lm;
                const float v = acc[i][j][r];
                if constexpr (MODE == 1) {
                    const u32 p = packhl(v);
                    u16* base = (u16*)Cbase + ((size_t)grow * (ldc >> 5) + (gcol >> 5)) * 64;
                    base[gcol & 31] = (u16)p;
                    base[32 + (gcol & 31)] = (u16)(p >> 16);
                } else if constexpr (MODE == 2) {
                    const int mv = Mbase[(long)bz * sM + (long)grow * ldc + gcol];
                    ((float*)Cbase)[(long)bz * sC + (long)grow * ldc + gcol] =
                        (mv > 0) ? fmaxf(v, 0.f) : MINV;
                } else {
                    ((float*)Cbase)[(long)bz * sC + (long)grow * ldc + gcol] = v;
                }
            }
        }
    }
}

// ---------------------------------------------------------------------------
// Row softmax over 2048 elements, in place + f16 copy for gemm3.
// ---------------------------------------------------------------------------
__global__ __launch_bounds__(256) void softmax2048(float* __restrict__ attn,
                                                   u16* __restrict__ attnH)
{
    const long row = blockIdx.x;
    float* p = attn + row * 2048;
    const int tid = threadIdx.x;

    float4 v0 = ((const float4*)p)[tid];
    float4 v1 = ((const float4*)p)[tid + 256];

    float mx = fmaxf(fmaxf(fmaxf(v0.x, v0.y), fmaxf(v0.z, v0.w)),
                     fmaxf(fmaxf(v1.x, v1.y), fmaxf(v1.z, v1.w)));
#pragma unroll
    for (int o = 32; o >= 1; o >>= 1)
        mx = fmaxf(mx, __shfl_xor(mx, o, 64));

    __shared__ float redm[4];
    __shared__ float reds[4];
    const int wid = tid >> 6, lane = tid & 63;
    if (lane == 0) redm[wid] = mx;
    __syncthreads();
    mx = fmaxf(fmaxf(redm[0], redm[1]), fmaxf(redm[2], redm[3]));

    float e[8];
    e[0] = __expf(v0.x - mx); e[1] = __expf(v0.y - mx);
    e[2] = __expf(v0.z - mx); e[3] = __expf(v0.w - mx);
    e[4] = __expf(v1.x - mx); e[5] = __expf(v1.y - mx);
    e[6] = __expf(v1.z - mx); e[7] = __expf(v1.w - mx);

    float s = ((e[0] + e[1]) + (e[2] + e[3])) + ((e[4] + e[5]) + (e[6] + e[7]));
#pragma unroll
    for (int o = 32; o >= 1; o >>= 1)
        s += __shfl_xor(s, o, 64);
    if (lane == 0) reds[wid] = s;
    __syncthreads();
    s = (reds[0] + reds[1]) + (reds[2] + reds[3]);

    const float inv = 1.0f / s;
    float o0 = e[0] * inv, o1 = e[1] * inv, o2 = e[2] * inv, o3 = e[3] * inv;
    float o4 = e[4] * inv, o5 = e[5] * inv, o6 = e[6] * inv, o7 = e[7] * inv;
    ((float4*)p)[tid]       = make_float4(o0, o1, o2, o3);
    ((float4*)p)[tid + 256] = make_float4(o4, o5, o6, o7);

    u16* ph = attnH + row * 2048;
    ((uint2*)ph)[tid] =
        make_uint2((u32)h2u((_Float16)o0) | ((u32)h2u((_Float16)o1) << 16),
                   (u32)h2u((_Float16)o2) | ((u32)h2u((_Float16)o3) << 16));
    ((uint2*)ph)[tid + 256] =
        make_uint2((u32)h2u((_Float16)o4) | ((u32)h2u((_Float16)o5) << 16),
                   (u32)h2u((_Float16)o6) | ((u32)h2u((_Float16)o7) << 16));
}

extern "C" void kernel_launch(void* const* d_in, const int* in_sizes, int n_in,
                              void* d_out, int out_size, void* d_ws, size_t ws_size,
                              hipStream_t stream)
{
    (void)in_sizes; (void)n_in; (void)out_size; (void)ws_size;

    const float* query = (const float*)d_in[0];  // B,N,H
    const float* value = (const float*)d_in[1];  // B,N,H
    const int*   mask  = (const int*)d_in[2];    // B,N,N
    const float* W     = (const float*)d_in[3];  // H,H

    float* out  = (float*)d_out;                           // B*N*H
    float* attn = out + (size_t)BATCH * SEQ * HID;         // B*N*N

    // workspace: Vp 64MB | Vt 32MB | Wtp 4MB   (100MB total)
    u16* Vp  = (u16*)d_ws;
    u16* Vt  = (u16*)((char*)d_ws + ((size_t)64 << 20));
    u16* Wtp = (u16*)((char*)d_ws + ((size_t)96 << 20));

    // region reuse (stream-ordered, no overlap in time):
    u16* interP = (u16*)d_out;   // out region; dead once gemm3 writes out
    u16* Qp     = (u16*)attn;    // attn region; dead once gemm2 writes attn
    u16* attnH  = Vp;            // Vp region;  dead once gemm2 completes

    static int attr_done = 0;
    if (!attr_done) {
        hipFuncSetAttribute((const void*)gemm_mfma<1>,
                            hipFuncAttributeMaxDynamicSharedMemorySize, 131072);
        hipFuncSetAttribute((const void*)gemm_mfma<2>,
                            hipFuncAttributeMaxDynamicSharedMemorySize, 131072);
        hipFuncSetAttribute((const void*)gemm_mfma<3>,
                            hipFuncAttributeMaxDynamicSharedMemorySize, 131072);
        attr_done = 1;
    }

    prep_v<<<dim3(HID / 64, SEQ / 64, BATCH), 256, 0, stream>>>(value, Vp, Vt);
    prep_w<<<dim3(HID / 64, HID / 64, 1), 256, 0, stream>>>(W, Wtp);
    prep_q<<<dim3(BATCH * SEQ), 256, 0, stream>>>(query, Qp);

    // gemm1: interP = split(Qp) @ Wtp^T   M=16384 N=1024 K=1024
    gemm_mfma<1><<<dim3(HID / 256, (BATCH * SEQ) / 256, 1), 512, 131072, stream>>>(
        (const char*)Qp, (const char*)Wtp, interP, nullptr,
        HID, 0, 0, 0, 0);

    // gemm2: logits = relu(interP @ Vp^T) masked -> attn (fp32)
    gemm_mfma<2><<<dim3(SEQ / 256, SEQ / 256, BATCH), 512, 131072, stream>>>(
        (const char*)interP, (const char*)Vp, attn, mask,
        SEQ, (long)SEQ * 4096, (long)SEQ * 4096, (long)SEQ * SEQ, (long)SEQ * SEQ);

    softmax2048<<<dim3(BATCH * SEQ), 256, 0, stream>>>(attn, attnH);

    // gemm3: out = attnH @ Vt   M=2048 N=1024 K=2048 (plain f16, 64 k/group)
    gemm_mfma<3><<<dim3(HID / 256, SEQ / 256, BATCH), 512, 131072, stream>>>(
        (const char*)attnH, (const char*)Vt, out, nullptr,
        HID, (long)SEQ * 4096, (long)HID * 4096, (long)SEQ * HID, 0);
}

// Round 3
// 717.183 us; speedup vs baseline: 1.4028x; 1.0294x over previous
//
#include <hip/hip_runtime.h>

// BilinearAttention B=8, N=2048, H=1024 — MFMA f16-split pipeline, v4:
// 256x256 8-wave double-buffered 4-phase schedule with TRUE counted vmcnt
// (T4): staging chunks are consumed phase-staggered, so waits are
// vmcnt(6)/vmcnt(6)/-/vmcnt(4), never 0 in the main loop.
//
// Global plane-grouped format for all GEMM operands: rows of 128-byte groups,
// group g covers k=[g*32,g*32+32) as [32 hi f16 | 32 lo f16]  (split operands)
// or k=[g*64,g*64+64) as [64 f16]                             (plain f16 operands).
// Every matrix here has a 4096-byte row stride and 32 k-groups.
//
//   prep_v : value fp32 -> Vp planes [b][n][g][hi|lo]  +  Vt f16 [b][h][n]
//   prep_w : W fp32 [k][n] -> Wtp planes [n][g][hi|lo]
//   prep_q : query fp32 -> Qp planes [b*m][g][hi|lo]   (parked in attn region)
//   gemm<1>: interP = split(Qp) @ Wtp   (3-MFMA split) -> planes in out region
//   gemm<2>: logits = relu(interP @ Vp^T) masked -> attn fp32
//   softmax: rowwise in place + f16 copy attnH (parked in dead Vp region)
//   gemm<3>: out = attnH @ Vt  (plain f16 MFMA)

typedef _Float16 half8 __attribute__((ext_vector_type(8)));
typedef float f32x4 __attribute__((ext_vector_type(4)));
typedef unsigned short u16;
typedef unsigned int u32;

#define BATCH 8
#define SEQ   2048
#define HID   1024
#define MINV  (-1e9f)

#define AS1 __attribute__((address_space(1)))
#define AS3 __attribute__((address_space(3)))

__device__ __forceinline__ u16 h2u(_Float16 h) { return __builtin_bit_cast(u16, h); }

// split fp32 -> (hi,lo) f16 packed into one u32 (hi in low half)
__device__ __forceinline__ u32 packhl(float x) {
    _Float16 h = (_Float16)x;
    _Float16 l = (_Float16)(x - (float)h);
    return (u32)h2u(h) | ((u32)h2u(l) << 16);
}

__device__ __forceinline__ void gload16(const char* g, AS3 char* l) {
    __builtin_amdgcn_global_load_lds((const AS1 void*)g, (AS3 void*)l, 16, 0, 0);
}

// ---------------------------------------------------------------------------
// prep_v: 64x64 tiles. Writes Vp (plane-grouped) coalesced and Vt (f16,
// transposed to [b][h][n]) via LDS transpose.
// ---------------------------------------------------------------------------
__global__ __launch_bounds__(256) void prep_v(const float* __restrict__ V,
                                              u16* __restrict__ Vp,
                                              u16* __restrict__ Vt)
{
    __shared__ __align__(16) u16 lt[64 * 72];
    const int b = blockIdx.z, n0 = blockIdx.y * 64, h0 = blockIdx.x * 64;
    const int t = threadIdx.x;
    const int r = t >> 4, c4 = (t & 15) * 4;
#pragma unroll
    for (int it = 0; it < 4; ++it) {
        const int rr = r + it * 16;
        const float4 x = *(const float4*)(V + ((size_t)b * SEQ + n0 + rr) * HID + h0 + c4);
        const float xs[4] = {x.x, x.y, x.z, x.w};
        u32 p[4];
#pragma unroll
        for (int e = 0; e < 4; ++e) {
            p[e] = packhl(xs[e]);
            lt[(c4 + e) * 72 + rr] = (u16)p[e];
        }
        const int g = (h0 + c4) >> 5, j = c4 & 31;
        u16* base = Vp + (((size_t)b * SEQ + n0 + rr) * 32 + g) * 64;
        *(uint2*)(base + j) = make_uint2((p[0] & 0xffffu) | (p[1] << 16),
                                         (p[2] & 0xffffu) | (p[3] << 16));
        *(uint2*)(base + 32 + j) = make_uint2((p[0] >> 16) | (p[1] & 0xffff0000u),
                                              (p[2] >> 16) | (p[3] & 0xffff0000u));
    }
    __syncthreads();
    const int hr = t >> 2, cc = (t & 3) * 2;
    uint4 v0 = *(const uint4*)&lt[hr * 72 + cc * 8];
    uint4 v1 = *(const uint4*)&lt[hr * 72 + cc * 8 + 8];
    u16* dst = Vt + ((size_t)b * HID + h0 + hr) * SEQ + n0 + cc * 8;
    *(uint4*)dst = v0;
    *(uint4*)(dst + 8) = v1;
}

// ---------------------------------------------------------------------------
// prep_w: W [k][n] fp32 -> Wtp planes [n][g][hi|lo], 64x64 LDS transpose.
// ---------------------------------------------------------------------------
__global__ __launch_bounds__(256) void prep_w(const float* __restrict__ W,
                                              u16* __restrict__ Wtp)
{
    __shared__ __align__(16) u32 lt[64 * 68];
    const int n0 = blockIdx.x * 64, k0 = blockIdx.y * 64;
    const int t = threadIdx.x;
    const int r = t >> 4, c4 = (t & 15) * 4;
#pragma unroll
    for (int it = 0; it < 4; ++it) {
        const int rr = r + it * 16;
        const float4 x = *(const float4*)(W + (size_t)(k0 + rr) * HID + n0 + c4);
        const float xs[4] = {x.x, x.y, x.z, x.w};
#pragma unroll
        for (int e = 0; e < 4; ++e) lt[(c4 + e) * 68 + rr] = packhl(xs[e]);
    }
    __syncthreads();
    const int n = t >> 2;
#pragma unroll
    for (int s = 0; s < 4; ++s) {
        const int ci = (t & 3) + s * 4;
        uint4 v = *(const uint4*)&lt[n * 68 + ci * 4];
        const int k = k0 + ci * 4;
        u16* base = Wtp + (((size_t)n0 + n) * 32 + (k >> 5)) * 64;
        const int j = k & 31;
        *(uint2*)(base + j) = make_uint2((v.x & 0xffffu) | (v.y << 16),
                                         (v.z & 0xffffu) | (v.w << 16));
        *(uint2*)(base + 32 + j) = make_uint2((v.x >> 16) | (v.y & 0xffff0000u),
                                              (v.z >> 16) | (v.w & 0xffff0000u));
    }
}

// ---------------------------------------------------------------------------
// prep_q: query fp32 [row][1024] -> Qp planes [row][g][hi|lo]. One block/row.
// ---------------------------------------------------------------------------
__global__ __launch_bounds__(256) void prep_q(const float* __restrict__ Q,
                                              u16* __restrict__ Qp)
{
    const size_t row = blockIdx.x;
    const int t = threadIdx.x;
    const float4 x = ((const float4*)(Q + row * HID))[t];
    const u32 p0 = packhl(x.x), p1 = packhl(x.y), p2 = packhl(x.z), p3 = packhl(x.w);
    const int k = t * 4;
    u16* base = Qp + (row * 32 + (k >> 5)) * 64;
    const int j = k & 31;
    *(uint2*)(base + j) = make_uint2((p0 & 0xffffu) | (p1 << 16),
                                     (p2 & 0xffffu) | (p3 << 16));
    *(uint2*)(base + 32 + j) = make_uint2((p0 >> 16) | (p1 & 0xffff0000u),
                                          (p2 >> 16) | (p3 & 0xffff0000u));
}

// ---------------------------------------------------------------------------
// MFMA cluster: 4 A-frags x 2 B-cols (split: 3 MFMAs/unit; plain: 2).
// ---------------------------------------------------------------------------
template <bool SPLIT>
__device__ __forceinline__ void cluster4x2(f32x4 (&acc)[8][4], int ib, int jb,
                                           const half8 (&ah)[4], const half8 (&al)[4],
                                           half8 bh0, half8 bl0, half8 bh1, half8 bl1)
{
#pragma unroll
    for (int f = 0; f < 4; ++f) {
#pragma unroll
        for (int jj = 0; jj < 2; ++jj) {
            const half8 bh = jj ? bh1 : bh0;
            const half8 bl = jj ? bl1 : bl0;
            f32x4 c = acc[ib + f][jb + jj];
            if constexpr (SPLIT) {
                c = __builtin_amdgcn_mfma_f32_16x16x32_f16(al[f], bh, c, 0, 0, 0);
                c = __builtin_amdgcn_mfma_f32_16x16x32_f16(ah[f], bl, c, 0, 0, 0);
                c = __builtin_amdgcn_mfma_f32_16x16x32_f16(ah[f], bh, c, 0, 0, 0);
            } else {
                c = __builtin_amdgcn_mfma_f32_16x16x32_f16(ah[f], bh, c, 0, 0, 0);
                c = __builtin_amdgcn_mfma_f32_16x16x32_f16(al[f], bl, c, 0, 0, 0);
            }
            acc[ib + f][jb + jj] = c;
        }
    }
}

// ---------------------------------------------------------------------------
// MFMA GEMM, 256x256 block tile, 8 waves (2m x 4n), double-buffered LDS
// (128KB), 4-phase K-step with counted vmcnt (never 0 in the main loop).
//
// Staging chunks (8KB = one gload16 across 512 thr = 64 rows x 128B):
//   A: chunks A0,A1 (rows 0-127 = half H0), A2,A3 (rows 128-255 = H1)
//   B: chunks B0,B1 (rows 0-127 = group G0), B2,B3 (rows 128-255 = G1)
// Fragment remap so each half/group is read in exactly one phase:
//   A frag i of wave wm -> row (i>>1)*64 + wm*32 + (i&1)*16   (i=0..7)
//   B col  j of wave wn -> row (j>>1)*128 + wn*32 + (j&1)*16  (j=0..3)
// Phases: 0: H0xG0 (reads H0,G0; issues A0'A1'B0'B1'; vmcnt(6) covers B2B3)
//         1: H0xG1 (reads G1;    issues B2'B3';       vmcnt(6) covers A2A3)
//         2: H1xG1 (reads H1;    issues A2'A3';       no wait)
//         3: H1xG0 (G0 from regs;                     vmcnt(4) covers next P0)
// Every chunk has >= 3 MFMA clusters of flight time (>2000cy >> ~900cy HBM).
// Last iteration peeled via uniform branches (vmcnt(2)/vmcnt(0), no issues).
//
// Within-row offsets XOR-swizzled by (row&7)<<4 on BOTH the per-lane global
// source and the ds_read address (involution -> consistent, conflict-free).
// MODE 1: A,B split planes, C plane-grouped out        [gemm1]
// MODE 2: A,B split planes, relu+mask epilogue, C fp32 [gemm2]
// MODE 3: A,B plain f16 (64 k/group), C fp32           [gemm3]
// ---------------------------------------------------------------------------
template <int MODE>
__global__ __launch_bounds__(512, 2) void gemm_mfma(
    const char* __restrict__ Abase, const char* __restrict__ Bbase,
    void* __restrict__ Cbase, const int* __restrict__ Mbase,
    int ldc, long sAb, long sBb, long sC, long sM)
{
    constexpr bool SPLIT = (MODE != 3);
    extern __shared__ __align__(16) char smem[];   // 2 x (A 32KB | B 32KB)

    // bijective XCD-aware block swizzle (all grids have nwg % 8 == 0)
    const int nx = gridDim.x, ny = gridDim.y;
    const int nxy = nx * ny;
    int wg = blockIdx.x + nx * (blockIdx.y + ny * blockIdx.z);
    const int cpx = (nxy * gridDim.z) >> 3;
    wg = (wg & 7) * cpx + (wg >> 3);
    const int bz = wg / nxy;
    const int rem = wg - bz * nxy;
    const int m0 = (rem / nx) * 256, n0 = (rem % nx) * 256;

    const int tid = threadIdx.x;
    const int w = tid >> 6, l = tid & 63;
    const int wm = w >> 2, wn = w & 3;            // 2 x 4 wave grid
    const int lm = l & 15, q = l >> 4;

    const char* Ab = Abase + (long)bz * sAb;
    const char* Bb = Bbase + (long)bz * sBb;

    // staging offsets (k-invariant): LDS slot -> inverse-swizzled global
    size_t aoffs[4], boffs[4];
    int dsto[4];
#pragma unroll
    for (int it = 0; it < 4; ++it) {
        const int off = it * 8192 + tid * 16;     // chunk it: rows [it*64, it*64+64)
        dsto[it] = off;
        const int row = off >> 7;
        const int swi = (off & 127) ^ ((row & 7) << 4);
        aoffs[it] = (size_t)(m0 + row) * 4096 + swi;
        boffs[it] = (size_t)(n0 + row) * 4096 + swi;
    }
    // fragment-read swizzled within-row offset (row&7 == lm&7 for all frags)
    const int wofs = (q * 16) ^ ((lm & 7) << 4);

    f32x4 acc[8][4];
#pragma unroll
    for (int i = 0; i < 8; ++i)
#pragma unroll
        for (int j = 0; j < 4; ++j) acc[i][j] = (f32x4){0.f, 0.f, 0.f, 0.f};

    AS3 char* lds = (AS3 char*)smem;

    // prologue: stage K-step 0 into buf 0, full drain once
#pragma unroll
    for (int it = 0; it < 4; ++it) gload16(Ab + aoffs[it], lds + dsto[it]);
#pragma unroll
    for (int it = 0; it < 4; ++it) gload16(Bb + boffs[it], lds + 32768 + dsto[it]);
    asm volatile("s_waitcnt vmcnt(0)" ::: "memory");
    __builtin_amdgcn_s_barrier();

    half8 ah[4], al[4];
    half8 b0h, b0l, b1h, b1l, b2h, b2l, b3h, b3l;

    for (int ks = 0; ks < 32; ++ks) {
        const int cur = ks & 1;
        const char* At = smem + cur * 65536;
        const char* Bt = At + 32768;
        AS3 char* ldsA = lds + (cur ^ 1) * 65536;
        AS3 char* ldsB = ldsA + 32768;
        const size_t kb = (size_t)(ks + 1) * 128;
        const bool more = (ks < 31);

        // ---- phase 0: read H0 + G0; issue A0'A1'B0'B1' ----
#pragma unroll
        for (int i = 0; i < 4; ++i) {
            const char* rp = At + ((i >> 1) * 64 + wm * 32 + (i & 1) * 16 + lm) * 128;
            ah[i] = *(const half8*)(rp + wofs);
            al[i] = *(const half8*)(rp + (wofs ^ 64));
        }
        {
            const char* cp0 = Bt + (wn * 32 + lm) * 128;
            b0h = *(const half8*)(cp0 + wofs);
            b0l = *(const half8*)(cp0 + (wofs ^ 64));
            const char* cp1 = Bt + (wn * 32 + 16 + lm) * 128;
            b1h = *(const half8*)(cp1 + wofs);
            b1l = *(const half8*)(cp1 + (wofs ^ 64));
        }
        if (more) {
            gload16(Ab + aoffs[0] + kb, ldsA + dsto[0]);
            gload16(Ab + aoffs[1] + kb, ldsA + dsto[1]);
            gload16(Bb + boffs[0] + kb, ldsB + dsto[0]);
            gload16(Bb + boffs[1] + kb, ldsB + dsto[1]);
            asm volatile("s_waitcnt vmcnt(6)" ::: "memory");   // B2,B3(cur) landed
        } else {
            asm volatile("s_waitcnt vmcnt(2)" ::: "memory");
        }
        __builtin_amdgcn_s_barrier();
        asm volatile("s_waitcnt lgkmcnt(0)" ::: "memory");
        __builtin_amdgcn_sched_barrier(0);
        __builtin_amdgcn_s_setprio(1);
        cluster4x2<SPLIT>(acc, 0, 0, ah, al, b0h, b0l, b1h, b1l);
        __builtin_amdgcn_s_setprio(0);
        __builtin_amdgcn_s_barrier();

        // ---- phase 1: read G1; issue B2'B3' ----
        {
            const char* cp2 = Bt + (128 + wn * 32 + lm) * 128;
            b2h = *(const half8*)(cp2 + wofs);
            b2l = *(const half8*)(cp2 + (wofs ^ 64));
            const char* cp3 = Bt + (128 + wn * 32 + 16 + lm) * 128;
            b3h = *(const half8*)(cp3 + wofs);
            b3l = *(const half8*)(cp3 + (wofs ^ 64));
        }
        if (more) {
            gload16(Bb + boffs[2] + kb, ldsB + dsto[2]);
            gload16(Bb + boffs[3] + kb, ldsB + dsto[3]);
            asm volatile("s_waitcnt vmcnt(6)" ::: "memory");   // A2,A3(cur) landed
        } else {
            asm volatile("s_waitcnt vmcnt(0)" ::: "memory");
        }
        __builtin_amdgcn_s_barrier();
        asm volatile("s_waitcnt lgkmcnt(0)" ::: "memory");
        __builtin_amdgcn_sched_barrier(0);
        __builtin_amdgcn_s_setprio(1);
        cluster4x2<SPLIT>(acc, 0, 2, ah, al, b2h, b2l, b3h, b3l);
        __builtin_amdgcn_s_setprio(0);
        __builtin_amdgcn_s_barrier();

        // ---- phase 2: read H1; issue A2'A3' ----
#pragma unroll
        for (int i = 0; i < 4; ++i) {
            const char* rp = At + (128 + (i >> 1) * 64 + wm * 32 + (i & 1) * 16 + lm) * 128;
            ah[i] = *(const half8*)(rp + wofs);
            al[i] = *(const half8*)(rp + (wofs ^ 64));
        }
        if (more) {
            gload16(Ab + aoffs[2] + kb, ldsA + dsto[2]);
            gload16(Ab + aoffs[3] + kb, ldsA + dsto[3]);
        }
        __builtin_amdgcn_s_barrier();
        asm volatile("s_waitcnt lgkmcnt(0)" ::: "memory");
        __builtin_amdgcn_sched_barrier(0);
        __builtin_amdgcn_s_setprio(1);
        cluster4x2<SPLIT>(acc, 4, 2, ah, al, b2h, b2l, b3h, b3l);
        __builtin_amdgcn_s_setprio(0);
        __builtin_amdgcn_s_barrier();

        // ---- phase 3: G0 from regs; wait next step's A0'A1'B0'B1' ----
        if (more) asm volatile("s_waitcnt vmcnt(4)" ::: "memory");
        __builtin_amdgcn_s_barrier();
        __builtin_amdgcn_s_setprio(1);
        cluster4x2<SPLIT>(acc, 4, 0, ah, al, b0h, b0l, b1h, b1l);
        __builtin_amdgcn_s_setprio(0);
        __builtin_amdgcn_s_barrier();
    }

    // ---- epilogue ----  C/D map: col = lane&15, row = (lane>>4)*4 + reg
#pragma unroll
    for (int i = 0; i < 8; ++i) {
        const int arow = (i >> 1) * 64 + wm * 32 + (i & 1) * 16 + q * 4;
#pragma unroll
        for (int r = 0; r < 4; ++r) {
            const int grow = m0 + arow + r;
#pragma unroll
            for (int j = 0; j < 4; ++j) {
                const int gcol = n0 + (j >> 1) * 128 + wn * 32 + (j & 1) * 16 + lm;
                const float v = acc[i][j][r];
                if constexpr (MODE == 1) {
                    const u32 p = packhl(v);
                    u16* base = (u16*)Cbase + ((size_t)grow * (ldc >> 5) + (gcol >> 5)) * 64;
                    base[gcol & 31] = (u16)p;
                    base[32 + (gcol & 31)] = (u16)(p >> 16);
                } else if constexpr (MODE == 2) {
                    const int mv = Mbase[(long)bz * sM + (long)grow * ldc + gcol];
                    ((float*)Cbase)[(long)bz * sC + (long)grow * ldc + gcol] =
                        (mv > 0) ? fmaxf(v, 0.f) : MINV;
                } else {
                    ((float*)Cbase)[(long)bz * sC + (long)grow * ldc + gcol] = v;
                }
            }
        }
    }
}

// ---------------------------------------------------------------------------
// Row softmax over 2048 elements, in place + f16 copy for gemm3.
// ---------------------------------------------------------------------------
__global__ __launch_bounds__(256) void softmax2048(float* __restrict__ attn,
                                                   u16* __restrict__ attnH)
{
    const long row = blockIdx.x;
    float* p = attn + row * 2048;
    const int tid = threadIdx.x;

    float4 v0 = ((const float4*)p)[tid];
    float4 v1 = ((const float4*)p)[tid + 256];

    float mx = fmaxf(fmaxf(fmaxf(v0.x, v0.y), fmaxf(v0.z, v0.w)),
                     fmaxf(fmaxf(v1.x, v1.y), fmaxf(v1.z, v1.w)));
#pragma unroll
    for (int o = 32; o >= 1; o >>= 1)
        mx = fmaxf(mx, __shfl_xor(mx, o, 64));

    __shared__ float redm[4];
    __shared__ float reds[4];
    const int wid = tid >> 6, lane = tid & 63;
    if (lane == 0) redm[wid] = mx;
    __syncthreads();
    mx = fmaxf(fmaxf(redm[0], redm[1]), fmaxf(redm[2], redm[3]));

    float e[8];
    e[0] = __expf(v0.x - mx); e[1] = __expf(v0.y - mx);
    e[2] = __expf(v0.z - mx); e[3] = __expf(v0.w - mx);
    e[4] = __expf(v1.x - mx); e[5] = __expf(v1.y - mx);
    e[6] = __expf(v1.z - mx); e[7] = __expf(v1.w - mx);

    float s = ((e[0] + e[1]) + (e[2] + e[3])) + ((e[4] + e[5]) + (e[6] + e[7]));
#pragma unroll
    for (int o = 32; o >= 1; o >>= 1)
        s += __shfl_xor(s, o, 64);
    if (lane == 0) reds[wid] = s;
    __syncthreads();
    s = (reds[0] + reds[1]) + (reds[2] + reds[3]);

    const float inv = 1.0f / s;
    float o0 = e[0] * inv, o1 = e[1] * inv, o2 = e[2] * inv, o3 = e[3] * inv;
    float o4 = e[4] * inv, o5 = e[5] * inv, o6 = e[6] * inv, o7 = e[7] * inv;
    ((float4*)p)[tid]       = make_float4(o0, o1, o2, o3);
    ((float4*)p)[tid + 256] = make_float4(o4, o5, o6, o7);

    u16* ph = attnH + row * 2048;
    ((uint2*)ph)[tid] =
        make_uint2((u32)h2u((_Float16)o0) | ((u32)h2u((_Float16)o1) << 16),
                   (u32)h2u((_Float16)o2) | ((u32)h2u((_Float16)o3) << 16));
    ((uint2*)ph)[tid + 256] =
        make_uint2((u32)h2u((_Float16)o4) | ((u32)h2u((_Float16)o5) << 16),
                   (u32)h2u((_Float16)o6) | ((u32)h2u((_Float16)o7) << 16));
}

extern "C" void kernel_launch(void* const* d_in, const int* in_sizes, int n_in,
                              void* d_out, int out_size, void* d_ws, size_t ws_size,
                              hipStream_t stream)
{
    (void)in_sizes; (void)n_in; (void)out_size; (void)ws_size;

    const float* query = (const float*)d_in[0];  // B,N,H
    const float* value = (const float*)d_in[1];  // B,N,H
    const int*   mask  = (const int*)d_in[2];    // B,N,N
    const float* W     = (const float*)d_in[3];  // H,H

    float* out  = (float*)d_out;                           // B*N*H
    float* attn = out + (size_t)BATCH * SEQ * HID;         // B*N*N

    // workspace: Vp 64MB | Vt 32MB | Wtp 4MB   (100MB total)
    u16* Vp  = (u16*)d_ws;
    u16* Vt  = (u16*)((char*)d_ws + ((size_t)64 << 20));
    u16* Wtp = (u16*)((char*)d_ws + ((size_t)96 << 20));

    // region reuse (stream-ordered, no overlap in time):
    u16* interP = (u16*)d_out;   // out region; dead once gemm3 writes out
    u16* Qp     = (u16*)attn;    // attn region; dead once gemm2 writes attn
    u16* attnH  = Vp;            // Vp region;  dead once gemm2 completes

    static int attr_done = 0;
    if (!attr_done) {
        hipFuncSetAttribute((const void*)gemm_mfma<1>,
                            hipFuncAttributeMaxDynamicSharedMemorySize, 131072);
        hipFuncSetAttribute((const void*)gemm_mfma<2>,
                            hipFuncAttributeMaxDynamicSharedMemorySize, 131072);
        hipFuncSetAttribute((const void*)gemm_mfma<3>,
                            hipFuncAttributeMaxDynamicSharedMemorySize, 131072);
        attr_done = 1;
    }

    prep_v<<<dim3(HID / 64, SEQ / 64, BATCH), 256, 0, stream>>>(value, Vp, Vt);
    prep_w<<<dim3(HID / 64, HID / 64, 1), 256, 0, stream>>>(W, Wtp);
    prep_q<<<dim3(BATCH * SEQ), 256, 0, stream>>>(query, Qp);

    // gemm1: interP = split(Qp) @ Wtp^T   M=16384 N=1024 K=1024
    gemm_mfma<1><<<dim3(HID / 256, (BATCH * SEQ) / 256, 1), 512, 131072, stream>>>(
        (const char*)Qp, (const char*)Wtp, interP, nullptr,
        HID, 0, 0, 0, 0);

    // gemm2: logits = relu(interP @ Vp^T) masked -> attn (fp32)
    gemm_mfma<2><<<dim3(SEQ / 256, SEQ / 256, BATCH), 512, 131072, stream>>>(
        (const char*)interP, (const char*)Vp, attn, mask,
        SEQ, (long)SEQ * 4096, (long)SEQ * 4096, (long)SEQ * SEQ, (long)SEQ * SEQ);

    softmax2048<<<dim3(BATCH * SEQ), 256, 0, stream>>>(attn, attnH);

    // gemm3: out = attnH @ Vt   M=2048 N=1024 K=2048 (plain f16, 64 k/group)
    gemm_mfma<3><<<dim3(HID / 256, SEQ / 256, BATCH), 512, 131072, stream>>>(
        (const char*)attnH, (const char*)Vt, out, nullptr,
        HID, (long)SEQ * 4096, (long)HID * 4096, (long)SEQ * HID, 0);
}